// Round 15
// baseline (1469.466 us; speedup 1.0000x reference)
//
#include <hip/hip_runtime.h>

// R15: GATE-SPLIT ACROSS 2 WAVES. Block = 128 thr (2 waves) per 2 sequences;
// 1024 blocks = 4 blocks/CU = 8 waves/CU = 2 waves/SIMD (waves_per_eu(2,2)).
//
// Why: R5-R14 proved the 1-wave structure cannot hold 208 weight floats in
// arch VGPRs (RA parks them in AGPRs, ~830 cyc/iter of v_accvgpr_read
// shuttles — VOP3P can't read AGPRs on gfx950, R13 assembler error), and a
// single wave/SIMD exposes ~1170 cyc/iter of trans/DS latency tails. Halving
// the per-wave weight set fixes BOTH: 104 floats + ~60 glue fits in 256 regs
// with no pressure (no parking), and 2 waves/SIMD hide each other's tails.
//
//   wave 0: rows i,f of unit j (+ z-rows: lanes 51..54 carry W_ih2[q] in the
//           i-slot -> z = W_ih2 . h1 falls out of the matvec, R11/R12 trick)
//   wave 1: rows g,o of unit j
//
// Per iteration n (R12's proven re-phased pipeline):
//   1. matvec over hrow=h1(n-1): 26kk x 4 pk_fma; wave0 z-lanes publish z(n-1)
//   2. barrier1
//   3. LSTM2 step n-1 (redundant in both waves; h2/c2 replicated bit-identical)
//   4. x(n) = input (warm) or h2(n-1) (future); own-gate activations
//   5. write own gates to LDS; barrier2; read other wave's gates
//   6. c1/h1 update (redundant, bit-identical); both waves write hrow
//      (identical values -> benign race, no 3rd barrier)
// Gate g uses tanh = 2*sigma-1 (unified per-wave scale/offset, same op count).

#define H1N  51
#define NP   26    // k-pairs: k=0..51; k=51 slot = bias (hrow[51]=1.0)
#define WAVE 64

typedef float v2f __attribute__((ext_vector_type(2)));

#define INV_LN2   1.44269504088896340736f
#define INV_LN2X2 2.88539008177792681472f

__device__ __forceinline__ float sigmoid_s(float xs) {   // input pre-scaled by 1/ln2
    return __builtin_amdgcn_rcpf(1.0f + __builtin_amdgcn_exp2f(-xs));
}
__device__ __forceinline__ float tanh_s2(float xs2) {    // input pre-scaled by 2/ln2
    float e = __builtin_amdgcn_exp2f(xs2);
    return fmaf(-2.0f, __builtin_amdgcn_rcpf(e + 1.0f), 1.0f);
}
__device__ __forceinline__ float tanh_nat(float x) {
    return tanh_s2(x * INV_LN2X2);
}
__device__ __forceinline__ float rdlane(float v, int k) {
    return __int_as_float(__builtin_amdgcn_readlane(__float_as_int(v), k));
}

__global__ __attribute__((amdgpu_flat_work_group_size(128, 128),
                          amdgpu_waves_per_eu(2, 2)))
void lstm_gs(const float* __restrict__ input,   // [B, T]
             const float* __restrict__ W_ih1,   // [204, 1]
             const float* __restrict__ W_hh1,   // [204, 51]
             const float* __restrict__ b_ih1,   // [204]
             const float* __restrict__ b_hh1,   // [204]
             const float* __restrict__ W_ih2,   // [4, 51]
             const float* __restrict__ W_hh2,   // [4, 1]
             const float* __restrict__ b_ih2,   // [4]
             const float* __restrict__ b_hh2,   // [4]
             float* __restrict__ out,           // [B, T+F]
             int T, int TF)
{
    const int tid = threadIdx.x;
    const int wv  = tid >> 6;            // 0: rows i,f   1: rows g,o
    const int j   = tid & (WAVE - 1);
    const bool jv = (j < H1N);
    const int jj  = jv ? j : 0;
    const float m = jv ? 1.0f : 0.0f;
    const bool isz = (wv == 0) && (j >= H1N) && (j < H1N + 4);
    const int  q   = isz ? (j - H1N) : 0;
    const float mz = isz ? 1.0f : 0.0f;
    const float s2q = (q == 2) ? INV_LN2X2 : INV_LN2;

    const int sA = 2 * blockIdx.x, sB = sA + 1;

    // Own rows: X = i (wv0) / g (wv1);  Y = f (wv0) / o (wv1).
    const int rX = (wv ? 2 : 0) * H1N + jj;
    const int rY = (wv ? 3 : 1) * H1N + jj;
    const float sX = wv ? INV_LN2X2 : INV_LN2;   // g is the tanh gate
    const float sY = INV_LN2;
    // Unified activation constants for the X row: sigma vs tanh=2*sigma-1.
    const float scX = wv ? 2.0f : 1.0f;
    const float ofX = wv ? -1.0f : 0.0f;

    v2f wX[NP], wY[NP];
#pragma unroll
    for (int kk = 0; kk < NP; ++kk) {
        const int k0 = 2*kk, k1 = k0 + 1;
        wX[kk].x = m*sX*W_hh1[rX*H1N + k0] + mz*s2q*W_ih2[q*H1N + k0];
        wY[kk].x = m*sY*W_hh1[rY*H1N + k0];
        if (k1 < H1N) {
            wX[kk].y = m*sX*W_hh1[rX*H1N + k1] + mz*s2q*W_ih2[q*H1N + k1];
            wY[kk].y = m*sY*W_hh1[rY*H1N + k1];
        } else {   // bias slot (hrow[51] == 1.0); z-rows get 0
            wX[kk].y = m*sX*(b_ih1[rX] + b_hh1[rX]);
            wY[kk].y = m*sY*(b_ih1[rY] + b_hh1[rY]);
        }
    }
#pragma unroll
    for (int kk = 0; kk < NP; ++kk)
        asm volatile("" : "+v"(wX[kk]), "+v"(wY[kk]));   // one-time anchor

    const float wxX = m*sX*W_ih1[rX];
    const float wxY = m*sY*W_ih1[rY];

    const float wh2_0 = INV_LN2*W_hh2[0], wh2_1 = INV_LN2*W_hh2[1];
    const float wh2_2 = INV_LN2X2*W_hh2[2], wh2_3 = INV_LN2*W_hh2[3];
    const float b2_0 = INV_LN2*(b_ih2[0] + b_hh2[0]), b2_1 = INV_LN2*(b_ih2[1] + b_hh2[1]);
    const float b2_2 = INV_LN2X2*(b_ih2[2] + b_hh2[2]), b2_3 = INV_LN2*(b_ih2[3] + b_hh2[3]);

    __shared__ __align__(16) float hrowA[WAVE];
    __shared__ __align__(16) float hrowB[WAVE];
    __shared__ __align__(16) float2 zAB[4];        // z: {seqA, seqB} per gate
    __shared__ __align__(16) float2 gex[2][2][WAVE]; // [wave][row X/Y][lane]
    hrowA[j] = (j == H1N) ? 1.0f : 0.0f;   // both waves write identical
    hrowB[j] = (j == H1N) ? 1.0f : 0.0f;
    __syncthreads();

    float c1A = 0.0f, c1B = 0.0f;                 // replicated in both waves
    float h2A = 0.0f, c2A = 0.0f, h2B = 0.0f, c2B = 0.0f;

    const float* __restrict__ xrowA = input + (long)sA * T;
    const float* __restrict__ xrowB = input + (long)sB * T;
    float* __restrict__ orow = out + (long)(wv ? sB : sA) * TF;  // my seq

    float xbufA = 0.0f, xbufB = 0.0f, obuf = 0.0f;

    // One iteration. DO_L2 / DO_FIN / XMODE are literal constants at every
    // call site (constant-folded). Barriers are block-uniform.
    auto iter = [&](int n, int DO_L2, int DO_FIN, int XMODE) {
        // ---- 1. matvec over h1(n-1) ----
        v2f aXA = {0.0f, 0.0f}, aYA = {0.0f, 0.0f};
        v2f aXB = {0.0f, 0.0f}, aYB = {0.0f, 0.0f};
#pragma unroll
        for (int kk = 0; kk < NP; ++kk) {
            const v2f hpA = *(const v2f*)&hrowA[2*kk];   // ds_read_b64 bcast
            const v2f hpB = *(const v2f*)&hrowB[2*kk];
            asm("v_pk_fma_f32 %0, %4, %6, %0\n\t"
                "v_pk_fma_f32 %1, %5, %6, %1\n\t"
                "v_pk_fma_f32 %2, %4, %7, %2\n\t"
                "v_pk_fma_f32 %3, %5, %7, %3"
                : "+v"(aXA), "+v"(aYA), "+v"(aXB), "+v"(aYB)
                : "v"(wX[kk]), "v"(wY[kk]), "v"(hpA), "v"(hpB));
        }
        const float sXA = aXA.x + aXA.y, sYA = aYA.x + aYA.y;
        const float sXB = aXB.x + aXB.y, sYB = aYB.x + aYB.y;
        if (isz) zAB[q] = make_float2(sXA, sXB);     // z(n-1), wave0 lanes 51..54
        __syncthreads();                              // barrier1

        // ---- 3. LSTM2 step n-1 (redundant; h2/c2 replicated) ----
        if (DO_L2) {
            const float4 zp0 = *(const float4*)&zAB[0];  // zA0,zB0,zA1,zB1
            const float4 zp1 = *(const float4*)&zAB[2];  // zA2,zB2,zA3,zB3
            {
                const float g2i = sigmoid_s(fmaf(wh2_0, h2A, b2_0 + zp0.x));
                const float g2f = sigmoid_s(fmaf(wh2_1, h2A, b2_1 + zp0.z));
                const float g2g = tanh_s2 (fmaf(wh2_2, h2A, b2_2 + zp1.x));
                const float g2o = sigmoid_s(fmaf(wh2_3, h2A, b2_3 + zp1.z));
                c2A = fmaf(g2f, c2A, g2i * g2g);
                h2A = g2o * tanh_nat(c2A);
            }
            {
                const float g2i = sigmoid_s(fmaf(wh2_0, h2B, b2_0 + zp0.y));
                const float g2f = sigmoid_s(fmaf(wh2_1, h2B, b2_1 + zp0.w));
                const float g2g = tanh_s2 (fmaf(wh2_2, h2B, b2_2 + zp1.y));
                const float g2o = sigmoid_s(fmaf(wh2_3, h2B, b2_3 + zp1.w));
                c2B = fmaf(g2f, c2B, g2i * g2g);
                h2B = g2o * tanh_nat(c2B);
            }
            const int tt = n - 1;
            const float h2mine = wv ? h2B : h2A;
            if (j == (tt & 63)) obuf = h2mine;       // predicated pack
            if ((tt & 63) == 63) orow[tt - 63 + j] = obuf;
        }

        // ---- 4-6. finish LSTM1 step n ----
        if (DO_FIN) {
            float xA, xB;
            if (XMODE == 0) {
                if ((n & 63) == 0) { xbufA = xrowA[n + j]; xbufB = xrowB[n + j]; }
                xA = rdlane(xbufA, n & 63);
                xB = rdlane(xbufB, n & 63);
            } else {
                xA = h2A;  xB = h2B;                 // h2(n-1), just updated
            }
            // Own-gate activations (X: sigma or tanh=2*sigma-1; Y: sigma).
            const float gXA = fmaf(scX, sigmoid_s(fmaf(wxX, xA, sXA)), ofX);
            const float gYA =            sigmoid_s(fmaf(wxY, xA, sYA));
            const float gXB = fmaf(scX, sigmoid_s(fmaf(wxX, xB, sXB)), ofX);
            const float gYB =            sigmoid_s(fmaf(wxY, xB, sYB));
            gex[wv][0][j] = make_float2(gXA, gXB);
            gex[wv][1][j] = make_float2(gYA, gYB);
            __syncthreads();                          // barrier2
            const float2 oX = gex[1 - wv][0][j];      // other wave's X row
            const float2 oY = gex[1 - wv][1][j];      // other wave's Y row
            // Gather i,f,g,o (identical operands in both waves).
            const float iA = wv ? oX.x : gXA, fA = wv ? oY.x : gYA;
            const float gA = wv ? gXA : oX.x, oA = wv ? gYA : oY.x;
            const float iB = wv ? oX.y : gXB, fB = wv ? oY.y : gYB;
            const float gB = wv ? gXB : oX.y, oB = wv ? gYB : oY.y;
            c1A = fmaf(fA, c1A, iA * gA);
            c1B = fmaf(fB, c1B, iB * gB);
            const float h1A = oA * tanh_nat(c1A);
            const float h1B = oB * tanh_nat(c1B);
            if (jv) { hrowA[j] = h1A; hrowB[j] = h1B; }  // both waves: identical
        }
    };

    // n=0: no LSTM2 yet.
    iter(0, 0, 1, 0);
    // Warm: n = 1..T-1 (x from input).
    for (int n = 1; n < T; ++n) iter(n, 1, 1, 0);
    // Boundary n=T: LSTM2 for T-1 (+flush), first feedback step.
    iter(T, 1, 1, 1);
    // Future: n = T+1..TF-1.
    for (int n = T + 1; n < TF; ++n) iter(n, 1, 1, 1);
    // Drain n=TF: LSTM2 for TF-1 (+final flush), no LSTM1 finish.
    iter(TF, 1, 0, 1);
}

extern "C" void kernel_launch(void* const* d_in, const int* in_sizes, int n_in,
                              void* d_out, int out_size, void* d_ws, size_t ws_size,
                              hipStream_t stream) {
    const float* input = (const float*)d_in[0];
    const float* W_ih1 = (const float*)d_in[1];
    const float* W_hh1 = (const float*)d_in[2];
    const float* b_ih1 = (const float*)d_in[3];
    const float* b_hh1 = (const float*)d_in[4];
    const float* W_ih2 = (const float*)d_in[5];
    const float* W_hh2 = (const float*)d_in[6];
    const float* b_ih2 = (const float*)d_in[7];
    const float* b_hh2 = (const float*)d_in[8];
    float* out = (float*)d_out;

    const int B  = 2048;
    const int T  = in_sizes[0] / B;      // 1024
    const int TF = out_size   / B;       // 1088

    lstm_gs<<<dim3(B / 2), dim3(128), 0, stream>>>(
        input, W_ih1, W_hh1, b_ih1, b_hh1, W_ih2, W_hh2, b_ih2, b_hh2,
        out, T, TF);
}